// Round 13
// baseline (131.251 us; speedup 1.0000x reference)
//
#include <hip/hip_runtime.h>
#include <hip/hip_cooperative_groups.h>

#define VV 9
#define CC 24
#define HFF 120
#define WFF 160
#define HW (HFF*WFF)
#define NPAIR 45
#define NOFF 36    // unordered off-diagonal pairs
#define CPL 6      // channels per lane (quad scheme)
#define NBKT 1728  // 12x12x12 spatial buckets (8^3 voxel cells)
#define NBKT_PAD 2048

namespace cg = cooperative_groups;

typedef _Float16 half2_t __attribute__((ext_vector_type(2)));
struct H2x4 { half2_t h[4]; };

__device__ __host__ __forceinline__ constexpr int triidx(int a, int b) {
  return a * VV - a * (a - 1) / 2 + (b - a);
}

__device__ __forceinline__ half2_t pack2(float a, float b) {
  return __builtin_bit_cast(half2_t, __builtin_amdgcn_cvt_pkrtz(a, b));
}

__device__ __forceinline__ float dot2acc(half2_t a, half2_t b, float c) {
#if __has_builtin(__builtin_amdgcn_fdot2)
  return __builtin_amdgcn_fdot2(a, b, c, false);
#else
  return c + (float)a[0] * (float)b[0] + (float)a[1] * (float)b[1];
#endif
}

__device__ __forceinline__ int bucket_key(int x, int y, int z) {
  int kx = min(max(x, 0) >> 3, 11);
  int ky = min(max(y, 0) >> 3, 11);
  int kz = min(max(z, 0) >> 3, 11);
  return (kx * 12 + ky) * 12 + kz;
}

// ==================== fused cooperative kernel (tier A) ====================
// phase0 zero -> sync -> phase1 transpose+hist -> sync -> phase2 scan+scatter+zstat
// -> sync -> phase3 main (chunk grid-stride, XCD-swizzled).
__global__ __launch_bounds__(256)
void vf_fused(const int* __restrict__ coords, const float* __restrict__ feats,
              const float* __restrict__ proj_feat, const float* __restrict__ proj_img,
              const float* __restrict__ origin, const float* __restrict__ W_vs,
              const float* __restrict__ b_vs, const float* __restrict__ voxel_size,
              const int* __restrict__ scale, const int* __restrict__ im_h_p,
              const int* __restrict__ im_w_p,
              int* __restrict__ hist, int* __restrict__ cnt,
              int2* __restrict__ cvox, uint4* __restrict__ tf,
              double* __restrict__ partials, float* __restrict__ out,
              int n, int nbq) {
  cg::grid_group grid = cg::this_grid();
  __shared__ int sOffs[NBKT_PAD];
  __shared__ int sh[256];
  __shared__ float sPFz[VV * 4], sPI[VV * 12];
  __shared__ float sPF[VV * 12], sB[VV], sW8b[NOFF];
  __shared__ float2 sWp2[NOFF * 4];
  __shared__ double sRed[3][4];
  __shared__ float sMuSd[2];

  const int tid = threadIdx.x;
  const int G = gridDim.x;
  const int gid = blockIdx.x * 256 + tid;
  const int gstride = G * 256;

  // ---- phase 0: zero hist + cnt ----
  for (int i = gid; i < NBKT_PAD; i += gstride) { hist[i] = 0; cnt[i] = 0; }
  grid.sync();

  // ---- phase 1: fp16 transpose (64B padded texels) + coord histogram ----
  for (int i = gid; i < VV * HW; i += gstride) {
    int v = i / HW;
    int hw = i - v * HW;
    const float* s = feats + (size_t)v * CC * HW + hw;
    uint4* d = tf + (size_t)i * 4;
#pragma unroll
    for (int lr = 0; lr < 4; ++lr) {
      H2x4 o;
      o.h[0] = pack2(s[(size_t)(6 * lr + 0) * HW], s[(size_t)(6 * lr + 1) * HW]);
      o.h[1] = pack2(s[(size_t)(6 * lr + 2) * HW], s[(size_t)(6 * lr + 3) * HW]);
      o.h[2] = pack2(s[(size_t)(6 * lr + 4) * HW], s[(size_t)(6 * lr + 5) * HW]);
      o.h[3] = half2_t{0, 0};
      d[lr] = __builtin_bit_cast(uint4, o);
    }
  }
  for (int i = gid; i < n; i += gstride) {
    int key = bucket_key(coords[i * 4 + 1], coords[i * 4 + 2], coords[i * 4 + 3]);
    atomicAdd(&hist[key], 1);
  }
  grid.sync();

  // ---- phase 2: redundant per-block scan + divide-free mask + scatter + z-partials ----
  {
    int loc[8];
    int s = 0;
#pragma unroll
    for (int j = 0; j < 8; ++j) loc[j] = hist[tid * 8 + j];
#pragma unroll
    for (int j = 0; j < 8; ++j) { int v = loc[j]; loc[j] = s; s += v; }
    sh[tid] = s;
    __syncthreads();
    for (int off = 1; off < 256; off <<= 1) {
      int v = (tid >= off) ? sh[tid - off] : 0;
      __syncthreads();
      sh[tid] += v;
      __syncthreads();
    }
    int base = sh[tid] - s;
#pragma unroll
    for (int j = 0; j < 8; ++j) sOffs[tid * 8 + j] = base + loc[j];
  }
  for (int t = tid; t < VV * 12; t += 256) {
    int v = t / 12, r = t - v * 12;
    sPI[t] = proj_img[v * 16 + r];
  }
  if (tid < VV * 4) {
    int v = tid >> 2, r = tid & 3;
    sPFz[tid] = proj_feat[v * 16 + 8 + r];   // pz row only
  }
  __syncthreads();
  {
    double zs = 0, zss = 0, zcn = 0;
    float vs = voxel_size[0];
    float half = ldexpf(0.5f * vs, scale[0]);
    float imw1 = (float)(im_w_p[0] - 1), imh1 = (float)(im_h_p[0] - 1);
    float cx2 = 2.f / imw1;   // divide-free: Z>0 && |X*cx2 - Z| <= 1.1*Z (R6/R9-proven)
    float cy2 = 2.f / imh1;
    for (int i = gid; i < n; i += gstride) {
      int x = coords[i * 4 + 1], y = coords[i * 4 + 2], z = coords[i * 4 + 3];
      int key = bucket_key(x, y, z);
      int rank = atomicAdd(&cnt[key], 1);
      float wxp = (float)x * vs + origin[0];
      float wyp = (float)y * vs + origin[1];
      float wzp = (float)z * vs + origin[2];
      int mkbits = 0;
      float zsum = 0.f, msum = 0.f;
#pragma unroll
      for (int v = 0; v < VV; ++v) {
        const float* R = &sPFz[v * 4];
        float pz = R[0] * wxp + R[1] * wyp + R[2] * wzp + R[3];
        const float* P = &sPI[v * 12];
        float qx = P[0] * wxp + P[1] * wyp + P[2] * wzp + P[3];
        float qy = P[4] * wxp + P[5] * wyp + P[6] * wzp + P[7];
        float qz = P[8] * wxp + P[9] * wyp + P[10] * wzp + P[11];
        float h0x = P[0] * half, h1x = P[1] * half, h2x = P[2] * half;
        float h0y = P[4] * half, h1y = P[5] * half, h2y = P[6] * half;
        float h0z = P[8] * half, h1z = P[9] * half, h2z = P[10] * half;
        bool m = false;
#pragma unroll
        for (int k = 0; k < 8; ++k) {
          float s0 = (k & 1) ? -1.f : 1.f;
          float s1 = (k & 2) ? -1.f : 1.f;
          float s2 = (k & 4) ? -1.f : 1.f;
          float X = qx + s0 * h0x + s1 * h1x + s2 * h2x;
          float Y = qy + s0 * h0y + s1 * h1y + s2 * h2y;
          float Z = qz + s0 * h0z + s1 * h1z + s2 * h2z;
          m = m || (Z > 0.f && fabsf(X * cx2 - Z) <= 1.1f * Z && fabsf(Y * cy2 - Z) <= 1.1f * Z);
        }
        if (m) {
          mkbits |= 1 << v;
          zsum += pz;
          msum += 1.f;
        }
      }
      float zmean = zsum / (msum + 1e-10f);
      if (zmean > 0.f) { zs += zmean; zss += (double)zmean * zmean; zcn += 1.0; }
      cvox[sOffs[key] + rank] = make_int2(x | (y << 7) | (z << 14) | (mkbits << 21), i);
    }
    // per-block z-stat reduce (deterministic: fixed per-thread voxel sequence)
#pragma unroll
    for (int off = 32; off > 0; off >>= 1) {
      zs += __shfl_down(zs, off);
      zss += __shfl_down(zss, off);
      zcn += __shfl_down(zcn, off);
    }
    int wid = tid >> 6, lane = tid & 63;
    if (lane == 0) { sRed[0][wid] = zs; sRed[1][wid] = zss; sRed[2][wid] = zcn; }
    __syncthreads();
    if (tid == 0) {
      double S = 0, SS = 0, CN = 0;
      for (int w2 = 0; w2 < 4; ++w2) { S += sRed[0][w2]; SS += sRed[1][w2]; CN += sRed[2][w2]; }
      partials[blockIdx.x * 3 + 0] = S;
      partials[blockIdx.x * 3 + 1] = SS;
      partials[blockIdx.x * 3 + 2] = CN;
    }
  }
  grid.sync();

  // ---- phase 3: main (redundant mu/sd reduce, then chunk loop) ----
  for (int t = tid; t < VV * 12; t += 256) {
    int v = t / 12, r = t - v * 12;
    sPF[t] = proj_feat[v * 16 + r];
  }
  {
    float* wp2f = (float*)sWp2;
    for (int t = tid; t < NOFF * VV; t += 256) {
      int p = t / 9, j = t - p * 9;
      int v = 0, rem = p;
      while (rem >= 8 - v) { rem -= 8 - v; ++v; }
      int w = v + 1 + rem;
      float val = W_vs[(v * 8 + (w - 1)) * 9 + j] + W_vs[(w * 8 + v) * 9 + j];
      if (j < 8) wp2f[p * 8 + j] = val;
      else sW8b[p] = val;
    }
  }
  if (tid < VV) sB[tid] = b_vs[tid];
  {
    double s = 0, ss = 0, cn = 0;
    for (int b = tid; b < G; b += 256) {
      s += partials[b * 3 + 0];
      ss += partials[b * 3 + 1];
      cn += partials[b * 3 + 2];
    }
#pragma unroll
    for (int off = 32; off > 0; off >>= 1) {
      s += __shfl_down(s, off);
      ss += __shfl_down(ss, off);
      cn += __shfl_down(cn, off);
    }
    int wid = tid >> 6, lane = tid & 63;
    if (lane == 0) { sRed[0][wid] = s; sRed[1][wid] = ss; sRed[2][wid] = cn; }
    __syncthreads();
    if (tid == 0) {
      double S = 0, SS = 0, CN = 0;
      for (int w2 = 0; w2 < 4; ++w2) { S += sRed[0][w2]; SS += sRed[1][w2]; CN += sRed[2][w2]; }
      double cnt2 = CN < 1.0 ? 1.0 : CN;
      double mu = S / cnt2;
      double ssd = SS - 2.0 * mu * S + mu * mu * CN;
      if (ssd < 0.0) ssd = 0.0;
      sMuSd[0] = (float)mu;
      sMuSd[1] = (float)(sqrt(ssd) + 1e-5);
    }
    __syncthreads();
  }
  float gmu = sMuSd[0], gsd = sMuSd[1];
  float vs = voxel_size[0];
  int lr = tid & 3;
  int vq = tid >> 2;
  // XCD-bijective swizzle over G (G % 8 == 0): same-XCD blocks own contiguous chunks
  int sblk = (blockIdx.x & 7) * (G >> 3) + (blockIdx.x >> 3);

  for (int cb = sblk; cb < nbq; cb += G) {
    int slot = cb * 64 + vq;
    bool active = slot < n;

    half2_t f[VV][CPL / 2];
    int mkbits = 0;
    float zmean = 0.f;
    int i0 = 0;

    if (active) {
      int2 pc = cvox[slot];
      int px_ = pc.x;
      int cx = px_ & 127, cy = (px_ >> 7) & 127, cz = (px_ >> 14) & 127;
      mkbits = (px_ >> 21) & 511;
      i0 = pc.y;
      float wxp = (float)cx * vs + origin[0];
      float wyp = (float)cy * vs + origin[1];
      float wzp = (float)cz * vs + origin[2];
      float zsum = 0.f;

#pragma unroll
      for (int v = 0; v < VV; ++v) {
        const float* M = &sPF[v * 12];
        float px = M[0] * wxp + M[1] * wyp + M[2] * wzp + M[3];
        float py = M[4] * wxp + M[5] * wyp + M[6] * wzp + M[7];
        float pz = M[8] * wxp + M[9] * wyp + M[10] * wzp + M[11];
        float mkv = (float)((mkbits >> v) & 1);
        zsum += pz * mkv;

        float rpz = 1.f / pz;
        float x = fminf(fmaxf(px * rpz, 0.f), (float)(WFF - 1));
        float y = fminf(fmaxf(py * rpz, 0.f), (float)(HFF - 1));
        float x0f = floorf(x), y0f = floorf(y);
        float fxv = x - x0f, fyv = y - y0f;
        int x0 = (int)x0f, y0 = (int)y0f;
        x0 = min(max(x0, 0), WFF - 1);
        y0 = min(max(y0, 0), HFF - 1);
        int x1 = min(x0 + 1, WFF - 1), y1 = min(y0 + 1, HFF - 1);
        int base16 = ((v * HFF + y0) * WFF + x0) * 4 + lr;
        int dx4 = (x1 - x0) * 4;
        int dy4 = (y1 - y0) * WFF * 4;
        float w00 = (1.f - fxv) * (1.f - fyv) * mkv;
        float w01 = fxv * (1.f - fyv) * mkv;
        float w10 = (1.f - fxv) * fyv * mkv;
        float w11 = fxv * fyv * mkv;
        half2_t W00 = pack2(w00, w00);
        half2_t W01 = pack2(w01, w01);
        half2_t W10 = pack2(w10, w10);
        half2_t W11 = pack2(w11, w11);

        const uint4* bp = tf + base16;
        H2x4 A = __builtin_bit_cast(H2x4, bp[0]);
        H2x4 B = __builtin_bit_cast(H2x4, bp[dx4]);
        H2x4 C = __builtin_bit_cast(H2x4, bp[dy4]);
        H2x4 D = __builtin_bit_cast(H2x4, bp[dx4 + dy4]);
#pragma unroll
        for (int j = 0; j < CPL / 2; ++j)
          f[v][j] = A.h[j] * W00 + B.h[j] * W01 + C.h[j] * W10 + D.h[j] * W11;
      }
      float msum = (float)__popc(mkbits);
      zmean = zsum / (msum + 1e-10f);
    } else {
#pragma unroll
      for (int v = 0; v < VV; ++v)
#pragma unroll
        for (int j = 0; j < CPL / 2; ++j) f[v][j] = half2_t{0, 0};
    }

    // partial gram (fp16 dot2, fp32 accum) + quad butterfly
    float gram[NPAIR];
    {
      int p = 0;
#pragma unroll
      for (int v = 0; v < VV; ++v)
#pragma unroll
        for (int w = v; w < VV; ++w, ++p) {
          float s = 0.f;
#pragma unroll
          for (int j = 0; j < CPL / 2; ++j) s = dot2acc(f[v][j], f[w][j], s);
          gram[p] = s;
        }
    }
#pragma unroll
    for (int p = 0; p < NPAIR; ++p) {
      gram[p] += __shfl_xor(gram[p], 1);
      gram[p] += __shfl_xor(gram[p], 2);
    }

    if (active) {
      float inv[VV];
#pragma unroll
      for (int v = 0; v < VV; ++v) inv[v] = 1.f / (sqrtf(gram[triidx(v, v)]) + 1e-10f);

      float l0 = 0.f, l1 = 0.f, l2 = 0.f;
      int pp = 0;
#pragma unroll
      for (int v = 0; v < VV; ++v) {
#pragma unroll
        for (int w = v + 1; w < VV; ++w, ++pp) {
          float s = gram[triidx(v, w)] * inv[v] * inv[w];
          float2 wp = sWp2[pp * 4 + lr];
          l0 += s * wp.x;
          l1 += s * wp.y;
          l2 += s * sW8b[pp];
        }
      }
      int qb = (tid & 63) & ~3;
      float logit[VV];
      logit[0] = __shfl(l0, qb + 0); logit[1] = __shfl(l1, qb + 0);
      logit[2] = __shfl(l0, qb + 1); logit[3] = __shfl(l1, qb + 1);
      logit[4] = __shfl(l0, qb + 2); logit[5] = __shfl(l1, qb + 2);
      logit[6] = __shfl(l0, qb + 3); logit[7] = __shfl(l1, qb + 3);
      logit[8] = l2;
#pragma unroll
      for (int j = 0; j < VV; ++j) logit[j] += sB[j];

      float mx = logit[0];
#pragma unroll
      for (int j = 1; j < VV; ++j) mx = fmaxf(mx, logit[j]);
      float wt[VV], se = 0.f;
#pragma unroll
      for (int j = 0; j < VV; ++j) {
        wt[j] = __expf(logit[j] - mx);
        se += wt[j];
      }
      float rse = 1.f / se;
#pragma unroll
      for (int j = 0; j < VV; ++j) wt[j] = ((mkbits >> j) & 1) ? wt[j] * rse : 0.f;

      half2_t acc[CPL / 2];
#pragma unroll
      for (int j = 0; j < CPL / 2; ++j) acc[j] = half2_t{0, 0};
#pragma unroll
      for (int v = 0; v < VV; ++v) {
        half2_t wv = pack2(wt[v], wt[v]);
#pragma unroll
        for (int j = 0; j < CPL / 2; ++j) acc[j] += f[v][j] * wv;
      }
      float* fvrow = out + (size_t)i0 * 25 + CPL * lr;
#pragma unroll
      for (int j = 0; j < CPL / 2; ++j) {
        fvrow[2 * j + 0] = (float)acc[j][0];
        fvrow[2 * j + 1] = (float)acc[j][1];
      }
      if (lr == 3)
        out[(size_t)i0 * 25 + CC] = (zmean > 0.f) ? (zmean - gmu) / gsd : 0.f;
      float* vwrow = out + (size_t)n * 25 + (size_t)i0 * 9;
      vwrow[lr] = wt[lr];
      vwrow[lr + 4] = wt[lr + 4];
      if (lr == 0) vwrow[8] = wt[8];
      if (lr == 1) out[(size_t)n * 34 + i0] = (float)__popc(mkbits);
    }
  }
}

// ==================== fallback: R12 4-dispatch path ====================
__global__ __launch_bounds__(256)
void k_t16_hist(const float* __restrict__ feats, uint4* __restrict__ tf,
                const int* __restrict__ coords, int* __restrict__ hist,
                int n, int nbt) {
  int b = blockIdx.x;
  if (b < nbt) {
    int i = b * 256 + threadIdx.x;
    if (i >= VV * HW) return;
    int v = i / HW;
    int hw = i - v * HW;
    const float* s = feats + (size_t)v * CC * HW + hw;
    uint4* d = tf + (size_t)i * 4;
#pragma unroll
    for (int lr = 0; lr < 4; ++lr) {
      H2x4 o;
      o.h[0] = pack2(s[(size_t)(6 * lr + 0) * HW], s[(size_t)(6 * lr + 1) * HW]);
      o.h[1] = pack2(s[(size_t)(6 * lr + 2) * HW], s[(size_t)(6 * lr + 3) * HW]);
      o.h[2] = pack2(s[(size_t)(6 * lr + 4) * HW], s[(size_t)(6 * lr + 5) * HW]);
      o.h[3] = half2_t{0, 0};
      d[lr] = __builtin_bit_cast(uint4, o);
    }
  } else {
    int i = (b - nbt) * 256 + threadIdx.x;
    if (i >= n) return;
    int key = bucket_key(coords[i * 4 + 1], coords[i * 4 + 2], coords[i * 4 + 3]);
    atomicAdd(&hist[key], 1);
  }
}

__global__ __launch_bounds__(256)
void k_scatter_zm(const int* __restrict__ coords, const int* __restrict__ hist,
                  int* __restrict__ cnt, int2* __restrict__ cvox,
                  const float* __restrict__ proj_feat,
                  const float* __restrict__ proj_img,
                  const float* __restrict__ origin,
                  const float* __restrict__ voxel_size,
                  const int* __restrict__ scale,
                  const int* __restrict__ im_h_p,
                  const int* __restrict__ im_w_p,
                  double* __restrict__ partials, int n) {
  __shared__ int sOffs[NBKT_PAD];
  __shared__ int sh[256];
  __shared__ float sPFz[VV * 4], sPI[VV * 12];
  __shared__ double sRed[3][4];
  int tid = threadIdx.x;
  {
    int loc[8];
    int s = 0;
#pragma unroll
    for (int j = 0; j < 8; ++j) loc[j] = hist[tid * 8 + j];
#pragma unroll
    for (int j = 0; j < 8; ++j) { int v = loc[j]; loc[j] = s; s += v; }
    sh[tid] = s;
    __syncthreads();
    for (int off = 1; off < 256; off <<= 1) {
      int v = (tid >= off) ? sh[tid - off] : 0;
      __syncthreads();
      sh[tid] += v;
      __syncthreads();
    }
    int base = sh[tid] - s;
#pragma unroll
    for (int j = 0; j < 8; ++j) sOffs[tid * 8 + j] = base + loc[j];
  }
  for (int t = tid; t < VV * 12; t += 256) {
    int v = t / 12, r = t - v * 12;
    sPI[t] = proj_img[v * 16 + r];
  }
  if (tid < VV * 4) {
    int v = tid >> 2, r = tid & 3;
    sPFz[tid] = proj_feat[v * 16 + 8 + r];
  }
  __syncthreads();

  int i = blockIdx.x * 256 + tid;
  float zmean = 0.f;
  if (i < n) {
    int x = coords[i * 4 + 1], y = coords[i * 4 + 2], z = coords[i * 4 + 3];
    int key = bucket_key(x, y, z);
    int rank = atomicAdd(&cnt[key], 1);
    float vs = voxel_size[0];
    float half = ldexpf(0.5f * vs, scale[0]);
    float wxp = (float)x * vs + origin[0];
    float wyp = (float)y * vs + origin[1];
    float wzp = (float)z * vs + origin[2];
    float imw1 = (float)(im_w_p[0] - 1), imh1 = (float)(im_h_p[0] - 1);
    float cx2 = 2.f / imw1;
    float cy2 = 2.f / imh1;
    int mkbits = 0;
    float zsum = 0.f, msum = 0.f;
#pragma unroll
    for (int v = 0; v < VV; ++v) {
      const float* R = &sPFz[v * 4];
      float pz = R[0] * wxp + R[1] * wyp + R[2] * wzp + R[3];
      const float* P = &sPI[v * 12];
      float qx = P[0] * wxp + P[1] * wyp + P[2] * wzp + P[3];
      float qy = P[4] * wxp + P[5] * wyp + P[6] * wzp + P[7];
      float qz = P[8] * wxp + P[9] * wyp + P[10] * wzp + P[11];
      float h0x = P[0] * half, h1x = P[1] * half, h2x = P[2] * half;
      float h0y = P[4] * half, h1y = P[5] * half, h2y = P[6] * half;
      float h0z = P[8] * half, h1z = P[9] * half, h2z = P[10] * half;
      bool m = false;
#pragma unroll
      for (int k = 0; k < 8; ++k) {
        float s0 = (k & 1) ? -1.f : 1.f;
        float s1 = (k & 2) ? -1.f : 1.f;
        float s2 = (k & 4) ? -1.f : 1.f;
        float X = qx + s0 * h0x + s1 * h1x + s2 * h2x;
        float Y = qy + s0 * h0y + s1 * h1y + s2 * h2y;
        float Z = qz + s0 * h0z + s1 * h1z + s2 * h2z;
        m = m || (Z > 0.f && fabsf(X * cx2 - Z) <= 1.1f * Z && fabsf(Y * cy2 - Z) <= 1.1f * Z);
      }
      if (m) {
        mkbits |= 1 << v;
        zsum += pz;
        msum += 1.f;
      }
    }
    zmean = zsum / (msum + 1e-10f);
    cvox[sOffs[key] + rank] = make_int2(x | (y << 7) | (z << 14) | (mkbits << 21), i);
  }

  bool pos = zmean > 0.f;
  double s = pos ? (double)zmean : 0.0;
  double ss = pos ? (double)zmean * (double)zmean : 0.0;
  double cn = pos ? 1.0 : 0.0;
#pragma unroll
  for (int off = 32; off > 0; off >>= 1) {
    s += __shfl_down(s, off);
    ss += __shfl_down(ss, off);
    cn += __shfl_down(cn, off);
  }
  int wid = tid >> 6, lane = tid & 63;
  if (lane == 0) { sRed[0][wid] = s; sRed[1][wid] = ss; sRed[2][wid] = cn; }
  __syncthreads();
  if (tid == 0) {
    double S = 0, SS = 0, CN = 0;
    for (int w2 = 0; w2 < 4; ++w2) { S += sRed[0][w2]; SS += sRed[1][w2]; CN += sRed[2][w2]; }
    partials[blockIdx.x * 3 + 0] = S;
    partials[blockIdx.x * 3 + 1] = SS;
    partials[blockIdx.x * 3 + 2] = CN;
  }
}

__global__ __launch_bounds__(256)
void vf_main4p(const int2* __restrict__ cvox,
               const uint4* __restrict__ tf,
               const float* __restrict__ proj_feat,
               const float* __restrict__ origin,
               const float* __restrict__ W_vs,
               const float* __restrict__ b_vs,
               const float* __restrict__ voxel_size,
               const int* __restrict__ scale,
               const double* __restrict__ partials,
               int nbz,
               float* __restrict__ out,
               int n) {
  __shared__ float sPF[VV * 12], sB[VV], sW8b[NOFF];
  __shared__ float2 sWp2[NOFF * 4];
  __shared__ double sRed[3][4];
  __shared__ float sMuSd[2];

  int tid = threadIdx.x;
  for (int t = tid; t < VV * 12; t += 256) {
    int v = t / 12, r = t - v * 12;
    sPF[t] = proj_feat[v * 16 + r];
  }
  {
    float* wp2f = (float*)sWp2;
    for (int t = tid; t < NOFF * VV; t += 256) {
      int p = t / 9, j = t - p * 9;
      int v = 0, rem = p;
      while (rem >= 8 - v) { rem -= 8 - v; ++v; }
      int w = v + 1 + rem;
      float val = W_vs[(v * 8 + (w - 1)) * 9 + j] + W_vs[(w * 8 + v) * 9 + j];
      if (j < 8) wp2f[p * 8 + j] = val;
      else sW8b[p] = val;
    }
  }
  if (tid < VV) sB[tid] = b_vs[tid];

  {
    double s = 0, ss = 0, cn = 0;
    for (int b = tid; b < nbz; b += 256) {
      s += partials[b * 3 + 0];
      ss += partials[b * 3 + 1];
      cn += partials[b * 3 + 2];
    }
#pragma unroll
    for (int off = 32; off > 0; off >>= 1) {
      s += __shfl_down(s, off);
      ss += __shfl_down(ss, off);
      cn += __shfl_down(cn, off);
    }
    int wid = tid >> 6, lane = tid & 63;
    if (lane == 0) { sRed[0][wid] = s; sRed[1][wid] = ss; sRed[2][wid] = cn; }
    __syncthreads();
    if (tid == 0) {
      double S = 0, SS = 0, CN = 0;
      for (int w2 = 0; w2 < 4; ++w2) { S += sRed[0][w2]; SS += sRed[1][w2]; CN += sRed[2][w2]; }
      double cnt2 = CN < 1.0 ? 1.0 : CN;
      double mu = S / cnt2;
      double ssd = SS - 2.0 * mu * S + mu * mu * CN;
      if (ssd < 0.0) ssd = 0.0;
      sMuSd[0] = (float)mu;
      sMuSd[1] = (float)(sqrt(ssd) + 1e-5);
    }
    __syncthreads();
  }
  float gmu = sMuSd[0], gsd = sMuSd[1];

  int nb = gridDim.x;
  int q = nb >> 3, r8 = nb & 7;
  int xcd = blockIdx.x & 7, idx = blockIdx.x >> 3;
  int sb = (xcd < r8 ? xcd * (q + 1) : r8 * (q + 1) + (xcd - r8) * q) + idx;

  int lr = tid & 3;
  int vq = tid >> 2;
  int slot = sb * 64 + vq;
  bool active = slot < n;

  half2_t f[VV][CPL / 2];
  int mkbits = 0;
  float zmean = 0.f;
  int i0 = 0;

  if (active) {
    int2 pc = cvox[slot];
    int px_ = pc.x;
    int cx = px_ & 127, cy = (px_ >> 7) & 127, cz = (px_ >> 14) & 127;
    mkbits = (px_ >> 21) & 511;
    i0 = pc.y;
    float vs = voxel_size[0];
    float wxp = (float)cx * vs + origin[0];
    float wyp = (float)cy * vs + origin[1];
    float wzp = (float)cz * vs + origin[2];
    float zsum = 0.f;

#pragma unroll
    for (int v = 0; v < VV; ++v) {
      const float* M = &sPF[v * 12];
      float px = M[0] * wxp + M[1] * wyp + M[2] * wzp + M[3];
      float py = M[4] * wxp + M[5] * wyp + M[6] * wzp + M[7];
      float pz = M[8] * wxp + M[9] * wyp + M[10] * wzp + M[11];
      float mkv = (float)((mkbits >> v) & 1);
      zsum += pz * mkv;

      float rpz = 1.f / pz;
      float x = fminf(fmaxf(px * rpz, 0.f), (float)(WFF - 1));
      float y = fminf(fmaxf(py * rpz, 0.f), (float)(HFF - 1));
      float x0f = floorf(x), y0f = floorf(y);
      float fxv = x - x0f, fyv = y - y0f;
      int x0 = (int)x0f, y0 = (int)y0f;
      x0 = min(max(x0, 0), WFF - 1);
      y0 = min(max(y0, 0), HFF - 1);
      int x1 = min(x0 + 1, WFF - 1), y1 = min(y0 + 1, HFF - 1);
      int base16 = ((v * HFF + y0) * WFF + x0) * 4 + lr;
      int dx4 = (x1 - x0) * 4;
      int dy4 = (y1 - y0) * WFF * 4;
      float w00 = (1.f - fxv) * (1.f - fyv) * mkv;
      float w01 = fxv * (1.f - fyv) * mkv;
      float w10 = (1.f - fxv) * fyv * mkv;
      float w11 = fxv * fyv * mkv;
      half2_t W00 = pack2(w00, w00);
      half2_t W01 = pack2(w01, w01);
      half2_t W10 = pack2(w10, w10);
      half2_t W11 = pack2(w11, w11);

      const uint4* bp = tf + base16;
      H2x4 A = __builtin_bit_cast(H2x4, bp[0]);
      H2x4 B = __builtin_bit_cast(H2x4, bp[dx4]);
      H2x4 C = __builtin_bit_cast(H2x4, bp[dy4]);
      H2x4 D = __builtin_bit_cast(H2x4, bp[dx4 + dy4]);
#pragma unroll
      for (int j = 0; j < CPL / 2; ++j)
        f[v][j] = A.h[j] * W00 + B.h[j] * W01 + C.h[j] * W10 + D.h[j] * W11;
    }
    float msum = (float)__popc(mkbits);
    zmean = zsum / (msum + 1e-10f);
  } else {
#pragma unroll
    for (int v = 0; v < VV; ++v)
#pragma unroll
      for (int j = 0; j < CPL / 2; ++j) f[v][j] = half2_t{0, 0};
  }

  float gram[NPAIR];
  {
    int p = 0;
#pragma unroll
    for (int v = 0; v < VV; ++v)
#pragma unroll
      for (int w = v; w < VV; ++w, ++p) {
        float s = 0.f;
#pragma unroll
        for (int j = 0; j < CPL / 2; ++j) s = dot2acc(f[v][j], f[w][j], s);
        gram[p] = s;
      }
  }
#pragma unroll
  for (int p = 0; p < NPAIR; ++p) {
    gram[p] += __shfl_xor(gram[p], 1);
    gram[p] += __shfl_xor(gram[p], 2);
  }

  if (active) {
    float inv[VV];
#pragma unroll
    for (int v = 0; v < VV; ++v) inv[v] = 1.f / (sqrtf(gram[triidx(v, v)]) + 1e-10f);

    float l0 = 0.f, l1 = 0.f, l2 = 0.f;
    int pp = 0;
#pragma unroll
    for (int v = 0; v < VV; ++v) {
#pragma unroll
      for (int w = v + 1; w < VV; ++w, ++pp) {
        float s = gram[triidx(v, w)] * inv[v] * inv[w];
        float2 wp = sWp2[pp * 4 + lr];
        l0 += s * wp.x;
        l1 += s * wp.y;
        l2 += s * sW8b[pp];
      }
    }
    int qb = (tid & 63) & ~3;
    float logit[VV];
    logit[0] = __shfl(l0, qb + 0); logit[1] = __shfl(l1, qb + 0);
    logit[2] = __shfl(l0, qb + 1); logit[3] = __shfl(l1, qb + 1);
    logit[4] = __shfl(l0, qb + 2); logit[5] = __shfl(l1, qb + 2);
    logit[6] = __shfl(l0, qb + 3); logit[7] = __shfl(l1, qb + 3);
    logit[8] = l2;
#pragma unroll
    for (int j = 0; j < VV; ++j) logit[j] += sB[j];

    float mx = logit[0];
#pragma unroll
    for (int j = 1; j < VV; ++j) mx = fmaxf(mx, logit[j]);
    float wt[VV], se = 0.f;
#pragma unroll
    for (int j = 0; j < VV; ++j) {
      wt[j] = __expf(logit[j] - mx);
      se += wt[j];
    }
    float rse = 1.f / se;
#pragma unroll
    for (int j = 0; j < VV; ++j) wt[j] = ((mkbits >> j) & 1) ? wt[j] * rse : 0.f;

    half2_t acc[CPL / 2];
#pragma unroll
    for (int j = 0; j < CPL / 2; ++j) acc[j] = half2_t{0, 0};
#pragma unroll
    for (int v = 0; v < VV; ++v) {
      half2_t wv = pack2(wt[v], wt[v]);
#pragma unroll
      for (int j = 0; j < CPL / 2; ++j) acc[j] += f[v][j] * wv;
    }
    float* fvrow = out + (size_t)i0 * 25 + CPL * lr;
#pragma unroll
    for (int j = 0; j < CPL / 2; ++j) {
      fvrow[2 * j + 0] = (float)acc[j][0];
      fvrow[2 * j + 1] = (float)acc[j][1];
    }
    if (lr == 3)
      out[(size_t)i0 * 25 + CC] = (zmean > 0.f) ? (zmean - gmu) / gsd : 0.f;
    float* vwrow = out + (size_t)n * 25 + (size_t)i0 * 9;
    vwrow[lr] = wt[lr];
    vwrow[lr + 4] = wt[lr + 4];
    if (lr == 0) vwrow[8] = wt[8];
    if (lr == 1) out[(size_t)n * 34 + i0] = (float)__popc(mkbits);
  }
}

extern "C" void kernel_launch(void* const* d_in, const int* in_sizes, int n_in,
                              void* d_out, int out_size, void* d_ws, size_t ws_size,
                              hipStream_t stream) {
  const int* coords = (const int*)d_in[0];
  const float* feats = (const float*)d_in[1];
  const float* proj_feat = (const float*)d_in[2];
  const float* proj_img = (const float*)d_in[3];
  const float* origin = (const float*)d_in[4];
  const float* W_vs = (const float*)d_in[5];
  const float* b_vs = (const float*)d_in[6];
  const float* voxel_size = (const float*)d_in[7];
  const int* scale = (const int*)d_in[8];
  const int* im_h = (const int*)d_in[9];
  const int* im_w = (const int*)d_in[10];
  float* outp = (float*)d_out;

  int n = in_sizes[0] / 4;
  int nbq = (n + 63) / 64;          // main chunks (64 voxels each)
  int nbz = (n + 255) / 256;        // per-voxel grids
  int nbt = (VV * HW + 255) / 256;  // transpose blocks
  const int MAXG = 2048;

  // workspace layout (hist & cnt adjacent)
  size_t off = 0;
  int* hist = (int*)((char*)d_ws + off);           off += NBKT_PAD * 4;
  int* cnt  = (int*)((char*)d_ws + off);           off += NBKT_PAD * 4;
  off = (off + 255) & ~(size_t)255;
  int nbp = nbz > MAXG ? nbz : MAXG;
  double* partials = (double*)((char*)d_ws + off); off += (size_t)nbp * 3 * 8;
  off = (off + 255) & ~(size_t)255;
  int2* cvox2 = (int2*)((char*)d_ws + off);        off += (size_t)n * 8;
  off = (off + 255) & ~(size_t)255;
  uint4* tf16 = (uint4*)((char*)d_ws + off);
  size_t tf16_bytes = (size_t)VV * HW * 64;   // padded 64B texels
  size_t need_full = off + tf16_bytes;
  if (ws_size < need_full) return;  // never observed; ws has held ~2x this since R2

  // ---- tier A0: single cooperative kernel ----
  bool done = false;
  int bpc = 0;
  if (hipOccupancyMaxActiveBlocksPerMultiprocessor(&bpc, vf_fused, 256, 0) == hipSuccess && bpc > 0) {
    int G = bpc * 256;               // 256 CUs on MI355X; mult of 8 by construction
    if (G > MAXG) G = MAXG;
    void* args[] = {
        (void*)&coords, (void*)&feats, (void*)&proj_feat, (void*)&proj_img,
        (void*)&origin, (void*)&W_vs, (void*)&b_vs, (void*)&voxel_size,
        (void*)&scale, (void*)&im_h, (void*)&im_w,
        (void*)&hist, (void*)&cnt, (void*)&cvox2, (void*)&tf16,
        (void*)&partials, (void*)&outp, (void*)&n, (void*)&nbq};
    if (hipLaunchCooperativeKernel(vf_fused, dim3(G), dim3(256), args, 0, stream) == hipSuccess)
      done = true;
  }
  if (done) return;

  // ---- tier A1: 4-dispatch fallback (R12 path, proven 130 us) ----
  (void)hipMemsetAsync(hist, 0, (size_t)NBKT_PAD * 2 * 4, stream);
  k_t16_hist<<<dim3(nbt + nbz), dim3(256), 0, stream>>>(feats, tf16, coords, hist, n, nbt);
  k_scatter_zm<<<dim3(nbz), dim3(256), 0, stream>>>(
      coords, hist, cnt, cvox2, proj_feat, proj_img, origin, voxel_size,
      scale, im_h, im_w, partials, n);
  vf_main4p<<<dim3(nbq), dim3(256), 0, stream>>>(
      cvox2, tf16, proj_feat, origin, W_vs, b_vs, voxel_size, scale,
      partials, nbz, (float*)d_out, n);
}

// Round 14
// 79.442 us; speedup vs baseline: 1.6522x; 1.6522x over previous
//
#include <hip/hip_runtime.h>

#define VV 9
#define CC 24
#define HFF 120
#define WFF 160
#define HW (HFF*WFF)
#define NPAIR 45
#define NOFF 36    // unordered off-diagonal pairs
#define CPL 6      // channels per lane (quad scheme)

typedef _Float16 half2_t __attribute__((ext_vector_type(2)));
struct H2x4 { half2_t h[4]; };

__device__ __host__ __forceinline__ constexpr int triidx(int a, int b) {
  return a * VV - a * (a - 1) / 2 + (b - a);
}

__device__ __forceinline__ half2_t pack2(float a, float b) {
  return __builtin_bit_cast(half2_t, __builtin_amdgcn_cvt_pkrtz(a, b));
}

__device__ __forceinline__ float dot2acc(half2_t a, half2_t b, float c) {
#if __has_builtin(__builtin_amdgcn_fdot2)
  return __builtin_amdgcn_fdot2(a, b, c, false);
#else
  return c + (float)a[0] * (float)b[0] + (float)a[1] * (float)b[1];
#endif
}

// ---------------- prep: transpose (blocks < nbt) || mask + z-partials (blocks >= nbt) ----------------
// NO sort, NO atomics (R14): mask stored per-voxel in original order; main indexes directly.
// tf texel = 64 B: 4 slots of 16 B (lane lr's 6 channels + 4 B pad) -> b128 gather loads.
__global__ __launch_bounds__(256)
void k_prep(const float* __restrict__ feats, uint4* __restrict__ tf,
            const int* __restrict__ coords, int* __restrict__ maskarr,
            const float* __restrict__ proj_feat, const float* __restrict__ proj_img,
            const float* __restrict__ origin, const float* __restrict__ voxel_size,
            const int* __restrict__ scale, const int* __restrict__ im_h_p,
            const int* __restrict__ im_w_p,
            double* __restrict__ partials, int n, int nbt) {
  int b = blockIdx.x;
  int tid = threadIdx.x;
  if (b < nbt) {
    int i = b * 256 + tid;
    if (i >= VV * HW) return;
    int v = i / HW;
    int hw = i - v * HW;
    const float* s = feats + (size_t)v * CC * HW + hw;
    uint4* d = tf + (size_t)i * 4;
#pragma unroll
    for (int lr = 0; lr < 4; ++lr) {
      H2x4 o;
      o.h[0] = pack2(s[(size_t)(6 * lr + 0) * HW], s[(size_t)(6 * lr + 1) * HW]);
      o.h[1] = pack2(s[(size_t)(6 * lr + 2) * HW], s[(size_t)(6 * lr + 3) * HW]);
      o.h[2] = pack2(s[(size_t)(6 * lr + 4) * HW], s[(size_t)(6 * lr + 5) * HW]);
      o.h[3] = half2_t{0, 0};
      d[lr] = __builtin_bit_cast(uint4, o);
    }
    return;
  }

  // ---- mask + z-stat partials, original voxel order, divide-free test (R6/R9-proven) ----
  __shared__ float sPFz[VV * 4], sPI[VV * 12];
  __shared__ double sRed[3][4];
  for (int t = tid; t < VV * 12; t += 256) {
    int v = t / 12, r = t - v * 12;
    sPI[t] = proj_img[v * 16 + r];
  }
  if (tid < VV * 4) {
    int v = tid >> 2, r = tid & 3;
    sPFz[tid] = proj_feat[v * 16 + 8 + r];   // pz row only
  }
  __syncthreads();

  int zb = b - nbt;
  int i = zb * 256 + tid;
  float zmean = 0.f;
  if (i < n) {
    int x = coords[i * 4 + 1], y = coords[i * 4 + 2], z = coords[i * 4 + 3];
    float vs = voxel_size[0];
    float half = ldexpf(0.5f * vs, scale[0]);
    float wxp = (float)x * vs + origin[0];
    float wyp = (float)y * vs + origin[1];
    float wzp = (float)z * vs + origin[2];
    float imw1 = (float)(im_w_p[0] - 1), imh1 = (float)(im_h_p[0] - 1);
    float cx2 = 2.f / imw1;
    float cy2 = 2.f / imh1;
    int mkbits = 0;
    float zsum = 0.f, msum = 0.f;
#pragma unroll
    for (int v = 0; v < VV; ++v) {
      const float* R = &sPFz[v * 4];
      float pz = R[0] * wxp + R[1] * wyp + R[2] * wzp + R[3];
      const float* P = &sPI[v * 12];
      float qx = P[0] * wxp + P[1] * wyp + P[2] * wzp + P[3];
      float qy = P[4] * wxp + P[5] * wyp + P[6] * wzp + P[7];
      float qz = P[8] * wxp + P[9] * wyp + P[10] * wzp + P[11];
      float h0x = P[0] * half, h1x = P[1] * half, h2x = P[2] * half;
      float h0y = P[4] * half, h1y = P[5] * half, h2y = P[6] * half;
      float h0z = P[8] * half, h1z = P[9] * half, h2z = P[10] * half;
      bool m = false;
#pragma unroll
      for (int k = 0; k < 8; ++k) {
        float s0 = (k & 1) ? -1.f : 1.f;
        float s1 = (k & 2) ? -1.f : 1.f;
        float s2 = (k & 4) ? -1.f : 1.f;
        float X = qx + s0 * h0x + s1 * h1x + s2 * h2x;
        float Y = qy + s0 * h0y + s1 * h1y + s2 * h2y;
        float Z = qz + s0 * h0z + s1 * h1z + s2 * h2z;
        m = m || (Z > 0.f && fabsf(X * cx2 - Z) <= 1.1f * Z && fabsf(Y * cy2 - Z) <= 1.1f * Z);
      }
      if (m) {
        mkbits |= 1 << v;
        zsum += pz;
        msum += 1.f;
      }
    }
    zmean = zsum / (msum + 1e-10f);
    maskarr[i] = mkbits;
  }

  bool pos = zmean > 0.f;
  double s = pos ? (double)zmean : 0.0;
  double ss = pos ? (double)zmean * (double)zmean : 0.0;
  double cn = pos ? 1.0 : 0.0;
#pragma unroll
  for (int off = 32; off > 0; off >>= 1) {
    s += __shfl_down(s, off);
    ss += __shfl_down(ss, off);
    cn += __shfl_down(cn, off);
  }
  int wid = tid >> 6, lane = tid & 63;
  if (lane == 0) { sRed[0][wid] = s; sRed[1][wid] = ss; sRed[2][wid] = cn; }
  __syncthreads();
  if (tid == 0) {
    double S = 0, SS = 0, CN = 0;
    for (int w2 = 0; w2 < 4; ++w2) { S += sRed[0][w2]; SS += sRed[1][w2]; CN += sRed[2][w2]; }
    partials[zb * 3 + 0] = S;
    partials[zb * 3 + 1] = SS;
    partials[zb * 3 + 2] = CN;
  }
}

// ---------------- main: 4 lanes/voxel, ORIGINAL order (no sort), padded-fp16 map ----------------
// Plain __launch_bounds__(256): min-waves clamp spills to scratch (R4 lesson).
__global__ __launch_bounds__(256)
void vf_main4u(const int* __restrict__ coords,
               const int* __restrict__ maskarr,
               const uint4* __restrict__ tf,
               const float* __restrict__ proj_feat,
               const float* __restrict__ origin,
               const float* __restrict__ W_vs,
               const float* __restrict__ b_vs,
               const float* __restrict__ voxel_size,
               const int* __restrict__ scale,
               const double* __restrict__ partials,
               int nbz,
               float* __restrict__ out,
               int n) {
  __shared__ float sPF[VV * 12], sB[VV], sW8b[NOFF];
  __shared__ float2 sWp2[NOFF * 4];
  __shared__ double sRed[3][4];
  __shared__ float sMuSd[2];

  int tid = threadIdx.x;
  for (int t = tid; t < VV * 12; t += 256) {
    int v = t / 12, r = t - v * 12;
    sPF[t] = proj_feat[v * 16 + r];
  }
  // wsym in-prologue (R12): lane-split layout cols{2l2,2l2+1} + col8
  {
    float* wp2f = (float*)sWp2;
    for (int t = tid; t < NOFF * VV; t += 256) {
      int p = t / 9, j = t - p * 9;
      int v = 0, rem = p;
      while (rem >= 8 - v) { rem -= 8 - v; ++v; }
      int w = v + 1 + rem;
      float val = W_vs[(v * 8 + (w - 1)) * 9 + j] + W_vs[(w * 8 + v) * 9 + j];
      if (j < 8) wp2f[p * 8 + j] = val;
      else sW8b[p] = val;
    }
  }
  if (tid < VV) sB[tid] = b_vs[tid];

  // redundant per-block mu/sd reduce (deterministic; partials L2-resident)
  {
    double s = 0, ss = 0, cn = 0;
    for (int b = tid; b < nbz; b += 256) {
      s += partials[b * 3 + 0];
      ss += partials[b * 3 + 1];
      cn += partials[b * 3 + 2];
    }
#pragma unroll
    for (int off = 32; off > 0; off >>= 1) {
      s += __shfl_down(s, off);
      ss += __shfl_down(ss, off);
      cn += __shfl_down(cn, off);
    }
    int wid = tid >> 6, lane = tid & 63;
    if (lane == 0) { sRed[0][wid] = s; sRed[1][wid] = ss; sRed[2][wid] = cn; }
    __syncthreads();
    if (tid == 0) {
      double S = 0, SS = 0, CN = 0;
      for (int w2 = 0; w2 < 4; ++w2) { S += sRed[0][w2]; SS += sRed[1][w2]; CN += sRed[2][w2]; }
      double cnt2 = CN < 1.0 ? 1.0 : CN;
      double mu = S / cnt2;
      double ssd = SS - 2.0 * mu * S + mu * mu * CN;
      if (ssd < 0.0) ssd = 0.0;
      sMuSd[0] = (float)mu;
      sMuSd[1] = (float)(sqrt(ssd) + 1e-5);
    }
    __syncthreads();
  }
  float gmu = sMuSd[0], gsd = sMuSd[1];

  int lr = tid & 3;       // lane-in-quad: channels [6*lr, 6*lr+6)
  int vq = tid >> 2;      // local voxel 0..63
  int vox = blockIdx.x * 64 + vq;
  bool active = vox < n;

  half2_t f[VV][CPL / 2];   // packed fp16 features
  int mkbits = 0;
  float zmean = 0.f;

  if (active) {
    mkbits = maskarr[vox];
    int cx = coords[vox * 4 + 1], cy = coords[vox * 4 + 2], cz = coords[vox * 4 + 3];
    float vs = voxel_size[0];
    float wxp = (float)cx * vs + origin[0];
    float wyp = (float)cy * vs + origin[1];
    float wzp = (float)cz * vs + origin[2];
    float zsum = 0.f;

#pragma unroll
    for (int v = 0; v < VV; ++v) {
      const float* M = &sPF[v * 12];
      float px = M[0] * wxp + M[1] * wyp + M[2] * wzp + M[3];
      float py = M[4] * wxp + M[5] * wyp + M[6] * wzp + M[7];
      float pz = M[8] * wxp + M[9] * wyp + M[10] * wzp + M[11];
      float mkv = (float)((mkbits >> v) & 1);
      zsum += pz * mkv;

      float rpz = 1.f / pz;
      float x = fminf(fmaxf(px * rpz, 0.f), (float)(WFF - 1));
      float y = fminf(fmaxf(py * rpz, 0.f), (float)(HFF - 1));
      float x0f = floorf(x), y0f = floorf(y);
      float fxv = x - x0f, fyv = y - y0f;
      int x0 = (int)x0f, y0 = (int)y0f;
      x0 = min(max(x0, 0), WFF - 1);
      y0 = min(max(y0, 0), HFF - 1);
      int x1 = min(x0 + 1, WFF - 1), y1 = min(y0 + 1, HFF - 1);
      // uint4 units: texel stride 4; lane slot +lr -> 16B-aligned b128 loads
      int base16 = ((v * HFF + y0) * WFF + x0) * 4 + lr;
      int dx4 = (x1 - x0) * 4;
      int dy4 = (y1 - y0) * WFF * 4;
      float w00 = (1.f - fxv) * (1.f - fyv) * mkv;
      float w01 = fxv * (1.f - fyv) * mkv;
      float w10 = (1.f - fxv) * fyv * mkv;
      float w11 = fxv * fyv * mkv;
      half2_t W00 = pack2(w00, w00);
      half2_t W01 = pack2(w01, w01);
      half2_t W10 = pack2(w10, w10);
      half2_t W11 = pack2(w11, w11);

      const uint4* bp = tf + base16;
      H2x4 A = __builtin_bit_cast(H2x4, bp[0]);
      H2x4 B = __builtin_bit_cast(H2x4, bp[dx4]);
      H2x4 C = __builtin_bit_cast(H2x4, bp[dy4]);
      H2x4 D = __builtin_bit_cast(H2x4, bp[dx4 + dy4]);
#pragma unroll
      for (int j = 0; j < CPL / 2; ++j)
        f[v][j] = A.h[j] * W00 + B.h[j] * W01 + C.h[j] * W10 + D.h[j] * W11;
    }
    float msum = (float)__popc(mkbits);
    zmean = zsum / (msum + 1e-10f);
  } else {
#pragma unroll
    for (int v = 0; v < VV; ++v)
#pragma unroll
      for (int j = 0; j < CPL / 2; ++j) f[v][j] = half2_t{0, 0};
  }

  // ---- partial gram over this lane's 6 channels (fp16 dot2, fp32 accum) ----
  float gram[NPAIR];
  {
    int p = 0;
#pragma unroll
    for (int v = 0; v < VV; ++v)
#pragma unroll
      for (int w = v; w < VV; ++w, ++p) {
        float s = 0.f;
#pragma unroll
        for (int j = 0; j < CPL / 2; ++j) s = dot2acc(f[v][j], f[w][j], s);
        gram[p] = s;
      }
  }
#pragma unroll
  for (int p = 0; p < NPAIR; ++p) {
    gram[p] += __shfl_xor(gram[p], 1);
    gram[p] += __shfl_xor(gram[p], 2);
  }

  if (active) {
    float inv[VV];
#pragma unroll
    for (int v = 0; v < VV; ++v) inv[v] = 1.f / (sqrtf(gram[triidx(v, v)]) + 1e-10f);

    // symmetrized logit matvec over 36 unordered pairs
    float l0 = 0.f, l1 = 0.f, l2 = 0.f;
    int pp = 0;
#pragma unroll
    for (int v = 0; v < VV; ++v) {
#pragma unroll
      for (int w = v + 1; w < VV; ++w, ++pp) {
        float s = gram[triidx(v, w)] * inv[v] * inv[w];
        float2 wp = sWp2[pp * 4 + lr];
        l0 += s * wp.x;
        l1 += s * wp.y;
        l2 += s * sW8b[pp];
      }
    }
    int qb = (tid & 63) & ~3;
    float logit[VV];
    logit[0] = __shfl(l0, qb + 0); logit[1] = __shfl(l1, qb + 0);
    logit[2] = __shfl(l0, qb + 1); logit[3] = __shfl(l1, qb + 1);
    logit[4] = __shfl(l0, qb + 2); logit[5] = __shfl(l1, qb + 2);
    logit[6] = __shfl(l0, qb + 3); logit[7] = __shfl(l1, qb + 3);
    logit[8] = l2;
#pragma unroll
    for (int j = 0; j < VV; ++j) logit[j] += sB[j];

    float mx = logit[0];
#pragma unroll
    for (int j = 1; j < VV; ++j) mx = fmaxf(mx, logit[j]);
    float wt[VV], se = 0.f;
#pragma unroll
    for (int j = 0; j < VV; ++j) {
      wt[j] = __expf(logit[j] - mx);
      se += wt[j];
    }
    float rse = 1.f / se;
#pragma unroll
    for (int j = 0; j < VV; ++j) wt[j] = ((mkbits >> j) & 1) ? wt[j] * rse : 0.f;

    // fused features: packed fp16 accumulate, fp32 store (contiguous rows)
    half2_t acc[CPL / 2];
#pragma unroll
    for (int j = 0; j < CPL / 2; ++j) acc[j] = half2_t{0, 0};
#pragma unroll
    for (int v = 0; v < VV; ++v) {
      half2_t wv = pack2(wt[v], wt[v]);
#pragma unroll
      for (int j = 0; j < CPL / 2; ++j) acc[j] += f[v][j] * wv;
    }
    float* fvrow = out + (size_t)vox * 25 + CPL * lr;
#pragma unroll
    for (int j = 0; j < CPL / 2; ++j) {
      fvrow[2 * j + 0] = (float)acc[j][0];
      fvrow[2 * j + 1] = (float)acc[j][1];
    }
    if (lr == 3)
      out[(size_t)vox * 25 + CC] = (zmean > 0.f) ? (zmean - gmu) / gsd : 0.f;
    float* vwrow = out + (size_t)n * 25 + (size_t)vox * 9;
    vwrow[lr] = wt[lr];
    vwrow[lr + 4] = wt[lr + 4];
    if (lr == 0) vwrow[8] = wt[8];
    if (lr == 1) out[(size_t)n * 34 + vox] = (float)__popc(mkbits);
  }
}

extern "C" void kernel_launch(void* const* d_in, const int* in_sizes, int n_in,
                              void* d_out, int out_size, void* d_ws, size_t ws_size,
                              hipStream_t stream) {
  const int* coords = (const int*)d_in[0];
  const float* feats = (const float*)d_in[1];
  const float* proj_feat = (const float*)d_in[2];
  const float* proj_img = (const float*)d_in[3];
  const float* origin = (const float*)d_in[4];
  const float* W_vs = (const float*)d_in[5];
  const float* b_vs = (const float*)d_in[6];
  const float* voxel_size = (const float*)d_in[7];
  const int* scale = (const int*)d_in[8];
  const int* im_h = (const int*)d_in[9];
  const int* im_w = (const int*)d_in[10];

  int n = in_sizes[0] / 4;
  int nbq = (n + 63) / 64;          // main blocks (64 voxels each)
  int nbz = (n + 255) / 256;        // mask blocks
  int nbt = (VV * HW + 255) / 256;  // transpose blocks

  // workspace layout: mask[n] | partials | tf16 (no hist/cnt/cvox — sort-free, atomic-free)
  size_t off = 0;
  int* maskarr = (int*)((char*)d_ws + off);        off += (size_t)n * 4;
  off = (off + 255) & ~(size_t)255;
  double* partials = (double*)((char*)d_ws + off); off += (size_t)nbz * 3 * 8;
  off = (off + 255) & ~(size_t)255;
  uint4* tf16 = (uint4*)((char*)d_ws + off);
  size_t tf16_bytes = (size_t)VV * HW * 64;   // padded 64B texels
  if (ws_size < off + tf16_bytes) return;     // never observed; ws has held ~2x this

  // ---- 2 dispatches, zero atomics ----
  k_prep<<<dim3(nbt + nbz), dim3(256), 0, stream>>>(
      feats, tf16, coords, maskarr, proj_feat, proj_img, origin, voxel_size,
      scale, im_h, im_w, partials, n, nbt);
  vf_main4u<<<dim3(nbq), dim3(256), 0, stream>>>(
      coords, maskarr, tf16, proj_feat, origin, W_vs, b_vs, voxel_size, scale,
      partials, nbz, (float*)d_out, n);
}

// Round 16
// 79.295 us; speedup vs baseline: 1.6552x; 1.0019x over previous
//
#include <hip/hip_runtime.h>

#define VV 9
#define CC 24
#define HFF 120
#define WFF 160
#define HW (HFF*WFF)
#define NPAIR 45
#define NOFF 36    // unordered off-diagonal pairs
#define CPL 6      // channels per lane (quad scheme)

typedef _Float16 half2_t __attribute__((ext_vector_type(2)));
struct H2x4 { half2_t h[4]; };

__device__ __host__ __forceinline__ constexpr int triidx(int a, int b) {
  return a * VV - a * (a - 1) / 2 + (b - a);
}

__device__ __forceinline__ half2_t pack2(float a, float b) {
  return __builtin_bit_cast(half2_t, __builtin_amdgcn_cvt_pkrtz(a, b));
}

__device__ __forceinline__ float dot2acc(half2_t a, half2_t b, float c) {
#if __has_builtin(__builtin_amdgcn_fdot2)
  return __builtin_amdgcn_fdot2(a, b, c, false);
#else
  return c + (float)a[0] * (float)b[0] + (float)a[1] * (float)b[1];
#endif
}

// ---------------- prep: transpose (blocks < nbt) || mask + z-partials (blocks >= nbt) ----------------
// NO sort, NO atomics (R14): mask stored per-voxel in original order; main indexes directly.
// tf texel = 64 B: 4 slots of 16 B (lane lr's 6 channels + 4 B pad) -> b128 gather loads.
__global__ __launch_bounds__(256)
void k_prep(const float* __restrict__ feats, uint4* __restrict__ tf,
            const int* __restrict__ coords, int* __restrict__ maskarr,
            const float* __restrict__ proj_feat, const float* __restrict__ proj_img,
            const float* __restrict__ origin, const float* __restrict__ voxel_size,
            const int* __restrict__ scale, const int* __restrict__ im_h_p,
            const int* __restrict__ im_w_p,
            double* __restrict__ partials, int n, int nbt) {
  int b = blockIdx.x;
  int tid = threadIdx.x;
  if (b < nbt) {
    int i = b * 256 + tid;
    if (i >= VV * HW) return;
    int v = i / HW;
    int hw = i - v * HW;
    const float* s = feats + (size_t)v * CC * HW + hw;
    uint4* d = tf + (size_t)i * 4;
#pragma unroll
    for (int lr = 0; lr < 4; ++lr) {
      H2x4 o;
      o.h[0] = pack2(s[(size_t)(6 * lr + 0) * HW], s[(size_t)(6 * lr + 1) * HW]);
      o.h[1] = pack2(s[(size_t)(6 * lr + 2) * HW], s[(size_t)(6 * lr + 3) * HW]);
      o.h[2] = pack2(s[(size_t)(6 * lr + 4) * HW], s[(size_t)(6 * lr + 5) * HW]);
      o.h[3] = half2_t{0, 0};
      d[lr] = __builtin_bit_cast(uint4, o);
    }
    return;
  }

  // ---- mask + z-stat partials, original voxel order, divide-free test (R6/R9-proven) ----
  __shared__ float sPFz[VV * 4], sPI[VV * 12];
  __shared__ double sRed[3][4];
  for (int t = tid; t < VV * 12; t += 256) {
    int v = t / 12, r = t - v * 12;
    sPI[t] = proj_img[v * 16 + r];
  }
  if (tid < VV * 4) {
    int v = tid >> 2, r = tid & 3;
    sPFz[tid] = proj_feat[v * 16 + 8 + r];   // pz row only
  }
  __syncthreads();

  int zb = b - nbt;
  int i = zb * 256 + tid;
  float zmean = 0.f;
  if (i < n) {
    int x = coords[i * 4 + 1], y = coords[i * 4 + 2], z = coords[i * 4 + 3];
    float vs = voxel_size[0];
    float half = ldexpf(0.5f * vs, scale[0]);
    float wxp = (float)x * vs + origin[0];
    float wyp = (float)y * vs + origin[1];
    float wzp = (float)z * vs + origin[2];
    float imw1 = (float)(im_w_p[0] - 1), imh1 = (float)(im_h_p[0] - 1);
    float cx2 = 2.f / imw1;
    float cy2 = 2.f / imh1;
    int mkbits = 0;
    float zsum = 0.f, msum = 0.f;
#pragma unroll
    for (int v = 0; v < VV; ++v) {
      const float* R = &sPFz[v * 4];
      float pz = R[0] * wxp + R[1] * wyp + R[2] * wzp + R[3];
      const float* P = &sPI[v * 12];
      float qx = P[0] * wxp + P[1] * wyp + P[2] * wzp + P[3];
      float qy = P[4] * wxp + P[5] * wyp + P[6] * wzp + P[7];
      float qz = P[8] * wxp + P[9] * wyp + P[10] * wzp + P[11];
      float h0x = P[0] * half, h1x = P[1] * half, h2x = P[2] * half;
      float h0y = P[4] * half, h1y = P[5] * half, h2y = P[6] * half;
      float h0z = P[8] * half, h1z = P[9] * half, h2z = P[10] * half;
      bool m = false;
#pragma unroll
      for (int k = 0; k < 8; ++k) {
        float s0 = (k & 1) ? -1.f : 1.f;
        float s1 = (k & 2) ? -1.f : 1.f;
        float s2 = (k & 4) ? -1.f : 1.f;
        float X = qx + s0 * h0x + s1 * h1x + s2 * h2x;
        float Y = qy + s0 * h0y + s1 * h1y + s2 * h2y;
        float Z = qz + s0 * h0z + s1 * h1z + s2 * h2z;
        m = m || (Z > 0.f && fabsf(X * cx2 - Z) <= 1.1f * Z && fabsf(Y * cy2 - Z) <= 1.1f * Z);
      }
      if (m) {
        mkbits |= 1 << v;
        zsum += pz;
        msum += 1.f;
      }
    }
    zmean = zsum / (msum + 1e-10f);
    maskarr[i] = mkbits;
  }

  bool pos = zmean > 0.f;
  double s = pos ? (double)zmean : 0.0;
  double ss = pos ? (double)zmean * (double)zmean : 0.0;
  double cn = pos ? 1.0 : 0.0;
#pragma unroll
  for (int off = 32; off > 0; off >>= 1) {
    s += __shfl_down(s, off);
    ss += __shfl_down(ss, off);
    cn += __shfl_down(cn, off);
  }
  int wid = tid >> 6, lane = tid & 63;
  if (lane == 0) { sRed[0][wid] = s; sRed[1][wid] = ss; sRed[2][wid] = cn; }
  __syncthreads();
  if (tid == 0) {
    double S = 0, SS = 0, CN = 0;
    for (int w2 = 0; w2 < 4; ++w2) { S += sRed[0][w2]; SS += sRed[1][w2]; CN += sRed[2][w2]; }
    partials[zb * 3 + 0] = S;
    partials[zb * 3 + 1] = SS;
    partials[zb * 3 + 2] = CN;
  }
}

// ---------------- main: 4 lanes/voxel, ORIGINAL order (no sort), padded-fp16 map ----------------
// Plain __launch_bounds__(256): min-waves clamp spills to scratch (R4 lesson).
// R16: exact revert to the proven R14 kernel. (R15's "linearized butterfly" was
// WRONG: per-lane partial sims were accumulated against per-lane weight columns,
// so the quad butterfly mixed different columns. The full 45-entry gram butterfly
// below is required for the lane-split matvec.)
__global__ __launch_bounds__(256)
void vf_main4u(const int* __restrict__ coords,
               const int* __restrict__ maskarr,
               const uint4* __restrict__ tf,
               const float* __restrict__ proj_feat,
               const float* __restrict__ origin,
               const float* __restrict__ W_vs,
               const float* __restrict__ b_vs,
               const float* __restrict__ voxel_size,
               const int* __restrict__ scale,
               const double* __restrict__ partials,
               int nbz,
               float* __restrict__ out,
               int n) {
  __shared__ float sPF[VV * 12], sB[VV], sW8b[NOFF];
  __shared__ float2 sWp2[NOFF * 4];
  __shared__ double sRed[3][4];
  __shared__ float sMuSd[2];

  int tid = threadIdx.x;
  for (int t = tid; t < VV * 12; t += 256) {
    int v = t / 12, r = t - v * 12;
    sPF[t] = proj_feat[v * 16 + r];
  }
  // wsym in-prologue (R12): lane-split layout cols{2l2,2l2+1} + col8
  {
    float* wp2f = (float*)sWp2;
    for (int t = tid; t < NOFF * VV; t += 256) {
      int p = t / 9, j = t - p * 9;
      int v = 0, rem = p;
      while (rem >= 8 - v) { rem -= 8 - v; ++v; }
      int w = v + 1 + rem;
      float val = W_vs[(v * 8 + (w - 1)) * 9 + j] + W_vs[(w * 8 + v) * 9 + j];
      if (j < 8) wp2f[p * 8 + j] = val;
      else sW8b[p] = val;
    }
  }
  if (tid < VV) sB[tid] = b_vs[tid];

  // redundant per-block mu/sd reduce (deterministic; partials L2-resident)
  {
    double s = 0, ss = 0, cn = 0;
    for (int b = tid; b < nbz; b += 256) {
      s += partials[b * 3 + 0];
      ss += partials[b * 3 + 1];
      cn += partials[b * 3 + 2];
    }
#pragma unroll
    for (int off = 32; off > 0; off >>= 1) {
      s += __shfl_down(s, off);
      ss += __shfl_down(ss, off);
      cn += __shfl_down(cn, off);
    }
    int wid = tid >> 6, lane = tid & 63;
    if (lane == 0) { sRed[0][wid] = s; sRed[1][wid] = ss; sRed[2][wid] = cn; }
    __syncthreads();
    if (tid == 0) {
      double S = 0, SS = 0, CN = 0;
      for (int w2 = 0; w2 < 4; ++w2) { S += sRed[0][w2]; SS += sRed[1][w2]; CN += sRed[2][w2]; }
      double cnt2 = CN < 1.0 ? 1.0 : CN;
      double mu = S / cnt2;
      double ssd = SS - 2.0 * mu * S + mu * mu * CN;
      if (ssd < 0.0) ssd = 0.0;
      sMuSd[0] = (float)mu;
      sMuSd[1] = (float)(sqrt(ssd) + 1e-5);
    }
    __syncthreads();
  }
  float gmu = sMuSd[0], gsd = sMuSd[1];

  int lr = tid & 3;       // lane-in-quad: channels [6*lr, 6*lr+6)
  int vq = tid >> 2;      // local voxel 0..63
  int vox = blockIdx.x * 64 + vq;
  bool active = vox < n;

  half2_t f[VV][CPL / 2];   // packed fp16 features
  int mkbits = 0;
  float zmean = 0.f;

  if (active) {
    mkbits = maskarr[vox];
    int cx = coords[vox * 4 + 1], cy = coords[vox * 4 + 2], cz = coords[vox * 4 + 3];
    float vs = voxel_size[0];
    float wxp = (float)cx * vs + origin[0];
    float wyp = (float)cy * vs + origin[1];
    float wzp = (float)cz * vs + origin[2];
    float zsum = 0.f;

#pragma unroll
    for (int v = 0; v < VV; ++v) {
      const float* M = &sPF[v * 12];
      float px = M[0] * wxp + M[1] * wyp + M[2] * wzp + M[3];
      float py = M[4] * wxp + M[5] * wyp + M[6] * wzp + M[7];
      float pz = M[8] * wxp + M[9] * wyp + M[10] * wzp + M[11];
      float mkv = (float)((mkbits >> v) & 1);
      zsum += pz * mkv;

      float rpz = 1.f / pz;
      float x = fminf(fmaxf(px * rpz, 0.f), (float)(WFF - 1));
      float y = fminf(fmaxf(py * rpz, 0.f), (float)(HFF - 1));
      float x0f = floorf(x), y0f = floorf(y);
      float fxv = x - x0f, fyv = y - y0f;
      int x0 = (int)x0f, y0 = (int)y0f;
      x0 = min(max(x0, 0), WFF - 1);
      y0 = min(max(y0, 0), HFF - 1);
      int x1 = min(x0 + 1, WFF - 1), y1 = min(y0 + 1, HFF - 1);
      // uint4 units: texel stride 4; lane slot +lr -> 16B-aligned b128 loads
      int base16 = ((v * HFF + y0) * WFF + x0) * 4 + lr;
      int dx4 = (x1 - x0) * 4;
      int dy4 = (y1 - y0) * WFF * 4;
      float w00 = (1.f - fxv) * (1.f - fyv) * mkv;
      float w01 = fxv * (1.f - fyv) * mkv;
      float w10 = (1.f - fxv) * fyv * mkv;
      float w11 = fxv * fyv * mkv;
      half2_t W00 = pack2(w00, w00);
      half2_t W01 = pack2(w01, w01);
      half2_t W10 = pack2(w10, w10);
      half2_t W11 = pack2(w11, w11);

      const uint4* bp = tf + base16;
      H2x4 A = __builtin_bit_cast(H2x4, bp[0]);
      H2x4 B = __builtin_bit_cast(H2x4, bp[dx4]);
      H2x4 C = __builtin_bit_cast(H2x4, bp[dy4]);
      H2x4 D = __builtin_bit_cast(H2x4, bp[dx4 + dy4]);
#pragma unroll
      for (int j = 0; j < CPL / 2; ++j)
        f[v][j] = A.h[j] * W00 + B.h[j] * W01 + C.h[j] * W10 + D.h[j] * W11;
    }
    float msum = (float)__popc(mkbits);
    zmean = zsum / (msum + 1e-10f);
  } else {
#pragma unroll
    for (int v = 0; v < VV; ++v)
#pragma unroll
      for (int j = 0; j < CPL / 2; ++j) f[v][j] = half2_t{0, 0};
  }

  // ---- partial gram over this lane's 6 channels (fp16 dot2, fp32 accum) ----
  float gram[NPAIR];
  {
    int p = 0;
#pragma unroll
    for (int v = 0; v < VV; ++v)
#pragma unroll
      for (int w = v; w < VV; ++w, ++p) {
        float s = 0.f;
#pragma unroll
        for (int j = 0; j < CPL / 2; ++j) s = dot2acc(f[v][j], f[w][j], s);
        gram[p] = s;
      }
  }
#pragma unroll
  for (int p = 0; p < NPAIR; ++p) {
    gram[p] += __shfl_xor(gram[p], 1);
    gram[p] += __shfl_xor(gram[p], 2);
  }

  if (active) {
    float inv[VV];
#pragma unroll
    for (int v = 0; v < VV; ++v) inv[v] = 1.f / (sqrtf(gram[triidx(v, v)]) + 1e-10f);

    // symmetrized logit matvec over 36 unordered pairs
    float l0 = 0.f, l1 = 0.f, l2 = 0.f;
    int pp = 0;
#pragma unroll
    for (int v = 0; v < VV; ++v) {
#pragma unroll
      for (int w = v + 1; w < VV; ++w, ++pp) {
        float s = gram[triidx(v, w)] * inv[v] * inv[w];
        float2 wp = sWp2[pp * 4 + lr];
        l0 += s * wp.x;
        l1 += s * wp.y;
        l2 += s * sW8b[pp];
      }
    }
    int qb = (tid & 63) & ~3;
    float logit[VV];
    logit[0] = __shfl(l0, qb + 0); logit[1] = __shfl(l1, qb + 0);
    logit[2] = __shfl(l0, qb + 1); logit[3] = __shfl(l1, qb + 1);
    logit[4] = __shfl(l0, qb + 2); logit[5] = __shfl(l1, qb + 2);
    logit[6] = __shfl(l0, qb + 3); logit[7] = __shfl(l1, qb + 3);
    logit[8] = l2;
#pragma unroll
    for (int j = 0; j < VV; ++j) logit[j] += sB[j];

    float mx = logit[0];
#pragma unroll
    for (int j = 1; j < VV; ++j) mx = fmaxf(mx, logit[j]);
    float wt[VV], se = 0.f;
#pragma unroll
    for (int j = 0; j < VV; ++j) {
      wt[j] = __expf(logit[j] - mx);
      se += wt[j];
    }
    float rse = 1.f / se;
#pragma unroll
    for (int j = 0; j < VV; ++j) wt[j] = ((mkbits >> j) & 1) ? wt[j] * rse : 0.f;

    // fused features: packed fp16 accumulate, fp32 store (contiguous rows)
    half2_t acc[CPL / 2];
#pragma unroll
    for (int j = 0; j < CPL / 2; ++j) acc[j] = half2_t{0, 0};
#pragma unroll
    for (int v = 0; v < VV; ++v) {
      half2_t wv = pack2(wt[v], wt[v]);
#pragma unroll
      for (int j = 0; j < CPL / 2; ++j) acc[j] += f[v][j] * wv;
    }
    float* fvrow = out + (size_t)vox * 25 + CPL * lr;
#pragma unroll
    for (int j = 0; j < CPL / 2; ++j) {
      fvrow[2 * j + 0] = (float)acc[j][0];
      fvrow[2 * j + 1] = (float)acc[j][1];
    }
    if (lr == 3)
      out[(size_t)vox * 25 + CC] = (zmean > 0.f) ? (zmean - gmu) / gsd : 0.f;
    float* vwrow = out + (size_t)n * 25 + (size_t)vox * 9;
    vwrow[lr] = wt[lr];
    vwrow[lr + 4] = wt[lr + 4];
    if (lr == 0) vwrow[8] = wt[8];
    if (lr == 1) out[(size_t)n * 34 + vox] = (float)__popc(mkbits);
  }
}

extern "C" void kernel_launch(void* const* d_in, const int* in_sizes, int n_in,
                              void* d_out, int out_size, void* d_ws, size_t ws_size,
                              hipStream_t stream) {
  const int* coords = (const int*)d_in[0];
  const float* feats = (const float*)d_in[1];
  const float* proj_feat = (const float*)d_in[2];
  const float* proj_img = (const float*)d_in[3];
  const float* origin = (const float*)d_in[4];
  const float* W_vs = (const float*)d_in[5];
  const float* b_vs = (const float*)d_in[6];
  const float* voxel_size = (const float*)d_in[7];
  const int* scale = (const int*)d_in[8];
  const int* im_h = (const int*)d_in[9];
  const int* im_w = (const int*)d_in[10];

  int n = in_sizes[0] / 4;
  int nbq = (n + 63) / 64;          // main blocks (64 voxels each)
  int nbz = (n + 255) / 256;        // mask blocks
  int nbt = (VV * HW + 255) / 256;  // transpose blocks

  // workspace layout: mask[n] | partials | tf16 (sort-free, atomic-free)
  size_t off = 0;
  int* maskarr = (int*)((char*)d_ws + off);        off += (size_t)n * 4;
  off = (off + 255) & ~(size_t)255;
  double* partials = (double*)((char*)d_ws + off); off += (size_t)nbz * 3 * 8;
  off = (off + 255) & ~(size_t)255;
  uint4* tf16 = (uint4*)((char*)d_ws + off);
  size_t tf16_bytes = (size_t)VV * HW * 64;   // padded 64B texels
  if (ws_size < off + tf16_bytes) return;     // never observed; ws has held ~2x this

  // ---- 2 dispatches, zero atomics ----
  k_prep<<<dim3(nbt + nbz), dim3(256), 0, stream>>>(
      feats, tf16, coords, maskarr, proj_feat, proj_img, origin, voxel_size,
      scale, im_h, im_w, partials, n, nbt);
  vf_main4u<<<dim3(nbq), dim3(256), 0, stream>>>(
      coords, maskarr, tf16, proj_feat, origin, W_vs, b_vs, voxel_size, scale,
      partials, nbz, (float*)d_out, n);
}